// Round 1
// baseline (1325.395 us; speedup 1.0000x reference)
//
#include <hip/hip_runtime.h>
#include <hip/hip_bf16.h>
#include <math.h>

#define T_DIM 4096
#define H_DIM 1024
#define NHEAD 4
#define TS_BLK 32   // timesteps per block in gemv kernel

// ---------------------------------------------------------------------------
// Kernel 1: h[b,t,n] = dot(x[b,t,:], W[n,:]) + bias[n]
// grid = (T/TS_BLK, B), block = 256 (4 waves). Each wave does one timestep at
// a time: 64 lanes * 4 float4 = 1024 floats coalesced; W cached in registers.
// ---------------------------------------------------------------------------
__global__ __launch_bounds__(256) void ema_gemv(const float* __restrict__ x,
                                                const float* __restrict__ W,
                                                const float* __restrict__ bias,
                                                float* __restrict__ h) {
    const int b    = blockIdx.y;
    const int t0   = blockIdx.x * TS_BLK;
    const int wave = threadIdx.x >> 6;
    const int lane = threadIdx.x & 63;

    // W fragment: lane holds W[n][c*256 + lane*4 .. +3] for n=0..3, c=0..3
    float4 wreg[NHEAD][4];
#pragma unroll
    for (int n = 0; n < NHEAD; ++n)
#pragma unroll
        for (int c = 0; c < 4; ++c)
            wreg[n][c] = *(const float4*)(W + n * H_DIM + c * 256 + lane * 4);

    const float4 bv = *(const float4*)bias;

    const int tpw = TS_BLK / 4;  // timesteps per wave
#pragma unroll 2
    for (int i = 0; i < tpw; ++i) {
        const int t = t0 + wave * tpw + i;
        const float* xr = x + ((size_t)b * T_DIM + t) * H_DIM;
        float4 xv[4];
#pragma unroll
        for (int c = 0; c < 4; ++c)
            xv[c] = *(const float4*)(xr + c * 256 + lane * 4);

        float acc[NHEAD] = {0.f, 0.f, 0.f, 0.f};
#pragma unroll
        for (int c = 0; c < 4; ++c) {
#pragma unroll
            for (int n = 0; n < NHEAD; ++n) {
                acc[n] += xv[c].x * wreg[n][c].x + xv[c].y * wreg[n][c].y
                        + xv[c].z * wreg[n][c].z + xv[c].w * wreg[n][c].w;
            }
        }
        // 64-lane butterfly reduce for all 4 heads
#pragma unroll
        for (int off = 32; off >= 1; off >>= 1)
#pragma unroll
            for (int n = 0; n < NHEAD; ++n)
                acc[n] += __shfl_xor(acc[n], off, 64);

        if (lane == 0) {
            float4 o;
            o.x = acc[0] + bv.x;
            o.y = acc[1] + bv.y;
            o.z = acc[2] + bv.z;
            o.w = acc[3] + bv.w;
            *(float4*)(h + ((size_t)b * T_DIM + t) * NHEAD) = o;
        }
    }
}

// ---------------------------------------------------------------------------
// Kernel 2: per-batch parallel EMA scan + running max + head projection.
// grid = B, block = 256. Thread i owns segment [16i, 16i+16).
// ema step is affine: e -> d*e + (1-d)*h_t. Segment = (A=d^16, B=local ema).
// Hillis-Steele inclusive scan over 256 segments (per head), then replay
// with carry-in tracking max (max includes the 0 init, matching reference).
// ---------------------------------------------------------------------------
__global__ __launch_bounds__(256) void ema_scan(const float* __restrict__ h,
                                                const float* __restrict__ decay,
                                                const float* __restrict__ head_w,
                                                float* __restrict__ out) {
    const int b    = blockIdx.x;
    const int i    = threadIdx.x;   // 0..255
    const int lane = i & 63;
    const int wave = i >> 6;

    float dd[NHEAD], od[NHEAD];
#pragma unroll
    for (int n = 0; n < NHEAD; ++n) {
        dd[n] = 1.0f / (1.0f + expf(-decay[n]));
        od[n] = 1.0f - dd[n];
    }

    const float4* hrow = (const float4*)(h + (size_t)b * T_DIM * NHEAD);

    // local segment EMA from zero init
    float e[NHEAD] = {0.f, 0.f, 0.f, 0.f};
#pragma unroll
    for (int j = 0; j < 16; ++j) {
        float4 v = hrow[i * 16 + j];
        e[0] = dd[0] * e[0] + od[0] * v.x;
        e[1] = dd[1] * e[1] + od[1] * v.y;
        e[2] = dd[2] * e[2] + od[2] * v.z;
        e[3] = dd[3] * e[3] + od[3] * v.w;
    }
    float a[NHEAD];
#pragma unroll
    for (int n = 0; n < NHEAD; ++n) {
        float d2 = dd[n] * dd[n];
        float d4 = d2 * d2;
        float d8 = d4 * d4;
        a[n] = d8 * d8;   // d^16
    }
    float bb[NHEAD] = {e[0], e[1], e[2], e[3]};

    __shared__ float sA[NHEAD][256];
    __shared__ float sB[NHEAD][256];
#pragma unroll
    for (int n = 0; n < NHEAD; ++n) { sA[n][i] = a[n]; sB[n][i] = bb[n]; }
    __syncthreads();

    for (int off = 1; off < 256; off <<= 1) {
        float pa[NHEAD], pb[NHEAD];
        const bool has = (i >= off);
        if (has) {
#pragma unroll
            for (int n = 0; n < NHEAD; ++n) {
                pa[n] = sA[n][i - off];
                pb[n] = sB[n][i - off];
            }
        }
        __syncthreads();
        if (has) {
#pragma unroll
            for (int n = 0; n < NHEAD; ++n) {
                bb[n] = a[n] * pb[n] + bb[n];  // B_new = A_cur*B_prev + B_cur
                a[n]  = a[n] * pa[n];          // A_new = A_cur*A_prev
            }
        }
#pragma unroll
        for (int n = 0; n < NHEAD; ++n) { sA[n][i] = a[n]; sB[n][i] = bb[n]; }
        __syncthreads();
    }

    // carry-in for my segment = inclusive B of segment i-1 (0 for i==0)
    float e2[NHEAD], m[NHEAD];
#pragma unroll
    for (int n = 0; n < NHEAD; ++n) {
        e2[n] = (i > 0) ? sB[n][i - 1] : 0.0f;
        m[n]  = 0.0f;   // reference's emax starts at 0
    }
#pragma unroll
    for (int j = 0; j < 16; ++j) {
        float4 v = hrow[i * 16 + j];
        e2[0] = dd[0] * e2[0] + od[0] * v.x; m[0] = fmaxf(m[0], e2[0]);
        e2[1] = dd[1] * e2[1] + od[1] * v.y; m[1] = fmaxf(m[1], e2[1]);
        e2[2] = dd[2] * e2[2] + od[2] * v.z; m[2] = fmaxf(m[2], e2[2]);
        e2[3] = dd[3] * e2[3] + od[3] * v.w; m[3] = fmaxf(m[3], e2[3]);
    }

    // 64-lane max butterfly, then cross-wave via LDS
#pragma unroll
    for (int off = 32; off >= 1; off >>= 1)
#pragma unroll
        for (int n = 0; n < NHEAD; ++n)
            m[n] = fmaxf(m[n], __shfl_xor(m[n], off, 64));

    __shared__ float sM[NHEAD][4];
    if (lane == 0) {
#pragma unroll
        for (int n = 0; n < NHEAD; ++n) sM[n][wave] = m[n];
    }
    __syncthreads();
    if (i == 0) {
        float o = 0.f;
#pragma unroll
        for (int n = 0; n < NHEAD; ++n) {
            float mm = fmaxf(fmaxf(sM[n][0], sM[n][1]), fmaxf(sM[n][2], sM[n][3]));
            o += mm * head_w[n];
        }
        out[b] = o;
    }
}

extern "C" void kernel_launch(void* const* d_in, const int* in_sizes, int n_in,
                              void* d_out, int out_size, void* d_ws, size_t ws_size,
                              hipStream_t stream) {
    const float* x      = (const float*)d_in[0];   // [B, T, H]
    const float* W      = (const float*)d_in[1];   // [NH, H]
    const float* bias   = (const float*)d_in[2];   // [NH]
    const float* decay  = (const float*)d_in[3];   // [NH]
    const float* head_w = (const float*)d_in[4];   // [1, NH]
    float* out = (float*)d_out;                    // [B]
    float* h   = (float*)d_ws;                     // [B, T, NH] scratch (4 MB)

    const int B = in_sizes[0] / (T_DIM * H_DIM);   // 64

    dim3 g1(T_DIM / TS_BLK, B);
    ema_gemv<<<g1, 256, 0, stream>>>(x, W, bias, h);
    ema_scan<<<B, 256, 0, stream>>>(h, decay, head_w, out);
}